// Round 1
// baseline (413.745 us; speedup 1.0000x reference)
//
#include <hip/hip_runtime.h>

typedef __bf16 bf16;
typedef __bf16 bf16x8 __attribute__((ext_vector_type(8)));
typedef float f32x4 __attribute__((ext_vector_type(4)));

#define EPS 1e-8f

constexpr int B = 16, CI = 256, CO = 256, S = 512, H = 64, W = 64;
constexpr int PH = 66;                    // padded spatial dim
constexpr int TAPS = 9;                   // 3x3

// workspace layout (bytes)
constexpr size_t WS_STYLE = 0;                                   // [B][CI] f32 = 16 KB
constexpr size_t WS_WD    = 16384;                               // [B][9][CO][CI] bf16 = 18.87 MB
constexpr size_t WS_XPAD  = WS_WD + (size_t)B * TAPS * CO * CI * 2; // [B][66][66][CI] bf16 = 35.68 MB

// ---------------------------------------------------------------- style ----
__global__ void style_kernel(const float* __restrict__ y,
                             const float* __restrict__ sw,
                             const float* __restrict__ sb,
                             float* __restrict__ style) {
    int b = blockIdx.x;
    int c = threadIdx.x;           // 256 threads, one per Cin
    const float* yrow = y + (size_t)b * S;
    const float* wrow = sw + (size_t)c * S;
    float acc = 0.f;
    for (int s = 0; s < S; ++s) acc += yrow[s] * wrow[s];
    style[b * CI + c] = acc + sb[c];
}

// ------------------------------------------------------------- modulate ----
// weights [CO][CI][3][3] f32 + style [B][CI] -> wd [B][tap][CO][CI] bf16
__global__ void modulate_kernel(const float* __restrict__ wts,
                                const float* __restrict__ style,
                                bf16* __restrict__ wd) {
    int co = blockIdx.x, b = blockIdx.y;
    __shared__ float m[CI * TAPS];
    __shared__ float red[4];
    const float* wrow = wts + (size_t)co * (CI * TAPS);
    const float* st = style + b * CI;

    float lsum = 0.f;
    for (int k = threadIdx.x; k < CI * TAPS; k += 256) {
        int ci = k / 9;
        float v = wrow[k] * st[ci];
        m[k] = v;
        lsum += v * v;
    }
    for (int off = 32; off; off >>= 1) lsum += __shfl_down(lsum, off, 64);
    int wave = threadIdx.x >> 6, lane = threadIdx.x & 63;
    if (lane == 0) red[wave] = lsum;
    __syncthreads();
    float tot = red[0] + red[1] + red[2] + red[3];
    float inv = 1.0f / sqrtf(tot + EPS);

    // write [tap][ci] for this (b,co): k = tap*256 + ci -> coalesced over ci
    for (int k = threadIdx.x; k < CI * TAPS; k += 256) {
        int tap = k >> 8, ci = k & 255;
        float v = m[ci * 9 + tap] * inv;
        wd[(((size_t)b * TAPS + tap) * CO + co) * CI + ci] = (bf16)v;
    }
}

// ----------------------------------------------------------------- xpad ----
// x [B][CI][H][W] f32 -> xp [B][PH][PH][CI] bf16 (interior only; rows/cols +1)
__global__ void xpad_kernel(const float* __restrict__ x, bf16* __restrict__ xp) {
    int cc = blockIdx.x;           // ci chunk of 32
    int h = blockIdx.y, b = blockIdx.z;
    __shared__ float t[32][W + 1];
    const float* src = x + ((size_t)b * CI + cc * 32) * (H * W) + (size_t)h * W;
    for (int e = threadIdx.x; e < 32 * W; e += 256) {
        int ci = e >> 6, w = e & 63;
        t[ci][w] = src[(size_t)ci * (H * W) + w];
    }
    __syncthreads();
    int w = threadIdx.x >> 2, cg = (threadIdx.x & 3) * 8;
    bf16x8 v;
#pragma unroll
    for (int j = 0; j < 8; ++j) v[j] = (bf16)t[cg + j][w];
    *(bf16x8*)(xp + (((size_t)b * PH + h + 1) * PH + (w + 1)) * CI + cc * 32 + cg) = v;
}

// --------------------------------------------------------------- border ----
__global__ void border_kernel(bf16* __restrict__ xp) {
    int r = blockIdx.x, b = blockIdx.y;
    bf16* row = xp + ((size_t)b * PH + r) * PH * CI;
    if (r == 0 || r == PH - 1) {
        for (int i = threadIdx.x; i < PH * CI; i += 256) row[i] = (bf16)0.f;
    } else {
        for (int i = threadIdx.x; i < 2 * CI; i += 256) {
            int col = (i < CI) ? 0 : (PH - 1);
            row[(size_t)col * CI + (i & 255)] = (bf16)0.f;
        }
    }
}

// ----------------------------------------------------------------- conv ----
// Implicit GEMM: D[co][sp] += sum_tap W_tap[co][ci] * X[ci][sp_shifted]
// Block: 256 thr = 4 waves; block tile 128co x (2 rows x 64 cols).
// Wave tile 64co x 64sp -> 4x4 mfma_f32_16x16x32_bf16 accumulators.
__global__ void conv_kernel(const bf16* __restrict__ wd,
                            const bf16* __restrict__ xp,
                            const float* __restrict__ bias,
                            float* __restrict__ out) {
    int cotile = blockIdx.x;       // 0..1
    int rowpair = blockIdx.y;      // 0..31
    int b = blockIdx.z;            // 0..15
    int tid = threadIdx.x;
    int wave = tid >> 6, lane = tid & 63;
    int co_half = wave & 1, sp_half = wave >> 1;
    int r = rowpair * 2 + sp_half;             // output row
    int co_base = cotile * 128 + co_half * 64; // + i*16
    int lm = lane & 15, lk = lane >> 4;

    f32x4 acc[4][4] = {};

    const bf16* wd_b = wd + (size_t)b * TAPS * CO * CI;
    const bf16* xp_b = xp + (size_t)b * PH * PH * CI;

#pragma unroll 1
    for (int ci0 = 0; ci0 < CI; ci0 += 32) {
        const bf16* wp = wd_b + (size_t)(co_base + lm) * CI + lk * 8 + ci0;
        const bf16* xq = xp_b + ((size_t)r * PH + lm) * CI + lk * 8 + ci0;
#pragma unroll
        for (int kh = 0; kh < 3; ++kh) {
#pragma unroll
            for (int kw = 0; kw < 3; ++kw) {
                const int tap = kh * 3 + kw;
                bf16x8 av[4], bv[4];
#pragma unroll
                for (int i = 0; i < 4; ++i)
                    av[i] = *(const bf16x8*)(wp + (size_t)tap * (CO * CI) + i * (16 * CI));
#pragma unroll
                for (int j = 0; j < 4; ++j)
                    bv[j] = *(const bf16x8*)(xq + (size_t)kh * (PH * CI) + kw * CI + j * (16 * CI));
#pragma unroll
                for (int i = 0; i < 4; ++i)
#pragma unroll
                    for (int j = 0; j < 4; ++j)
                        acc[i][j] = __builtin_amdgcn_mfma_f32_16x16x32_bf16(av[i], bv[j], acc[i][j], 0, 0, 0);
            }
        }
    }

    // epilogue: D row = lk*4 + reg (co), col = lm (+ j*16)
#pragma unroll
    for (int i = 0; i < 4; ++i) {
#pragma unroll
        for (int g = 0; g < 4; ++g) {
            int co = co_base + i * 16 + lk * 4 + g;
            float bvl = bias[co];
            size_t o = (((size_t)b * CO + co) * H + r) * W;
#pragma unroll
            for (int j = 0; j < 4; ++j)
                out[o + j * 16 + lm] = acc[i][j][g] + bvl;
        }
    }
}

// --------------------------------------------------------------- launch ----
extern "C" void kernel_launch(void* const* d_in, const int* in_sizes, int n_in,
                              void* d_out, int out_size, void* d_ws, size_t ws_size,
                              hipStream_t stream) {
    const float* x    = (const float*)d_in[0];
    const float* y    = (const float*)d_in[1];
    const float* wts  = (const float*)d_in[2];
    const float* bias = (const float*)d_in[3];
    const float* sw   = (const float*)d_in[4];
    const float* sb   = (const float*)d_in[5];
    float* out = (float*)d_out;

    char* ws = (char*)d_ws;
    float* style = (float*)(ws + WS_STYLE);
    bf16* wd   = (bf16*)(ws + WS_WD);
    bf16* xpad = (bf16*)(ws + WS_XPAD);

    style_kernel<<<dim3(B), dim3(CI), 0, stream>>>(y, sw, sb, style);
    modulate_kernel<<<dim3(CO, B), dim3(256), 0, stream>>>(wts, style, wd);
    xpad_kernel<<<dim3(CI / 32, H, B), dim3(256), 0, stream>>>(x, xpad);
    border_kernel<<<dim3(PH, B), dim3(256), 0, stream>>>(xpad);
    conv_kernel<<<dim3(2, 32, B), dim3(256), 0, stream>>>(wd, xpad, bias, out);
}

// Round 2
// 253.750 us; speedup vs baseline: 1.6305x; 1.6305x over previous
//
#include <hip/hip_runtime.h>

typedef __bf16 bf16;
typedef __bf16 bf16x8 __attribute__((ext_vector_type(8)));
typedef float f32x4 __attribute__((ext_vector_type(4)));

#define EPS 1e-8f

constexpr int B = 16, CI = 256, CO = 256, S = 512, H = 64, W = 64;
constexpr int PH = 66;                    // padded spatial dim
constexpr int TAPS = 9;                   // 3x3

// 16-byte "chunks" (8 bf16):
//   wd   chunks: [b][tap][ci8=32][co=256]   -> A-frag loads are 4x256B dense
//   xpad chunks: [b][row=66][ci8=32][col=66]-> B-frag loads are 4x256B dense,
//                                              kw shift only moves col
constexpr size_t WD_BYTES = (size_t)B * TAPS * 32 * CO * 16;   // 18,874,368
constexpr size_t XP_BYTES = (size_t)B * PH * 32 * PH * 16;     // 35,684,352
constexpr size_t WS_WD    = 0;
constexpr size_t WS_XPAD  = WD_BYTES;
// temporaries overlaid on the xpad region (consumed before xpad is written;
// same-stream ordering guarantees safety)
constexpr size_t WS_STYLE = WS_XPAD;            // f32 [B][CI]   = 16 KB
constexpr size_t WS_SUMSQ = WS_XPAD + 16384;    // f32 [B][CO]   = 16 KB
constexpr size_t WS_WTST  = WS_XPAD + 32768;    // f32 [9][CI][CO] = 2.36 MB

// ---------------------------------------------------------------- style ----
__global__ void style_kernel(const float* __restrict__ y,
                             const float* __restrict__ sw,
                             const float* __restrict__ sb,
                             float* __restrict__ style) {
    int b = blockIdx.x;
    int c = threadIdx.x;           // 256 threads, one per Cin
    const float* yrow = y + (size_t)b * S;
    const float* wrow = sw + (size_t)c * S;
    float acc = 0.f;
    for (int s = 0; s < S; ++s) acc += yrow[s] * wrow[s];
    style[b * CI + c] = acc + sb[c];
}

// ------------------------------------------------------------ transpose ----
// wts [CO][CI][3][3] f32 -> wtsT [tap][CI][CO] f32 (once per launch)
__global__ void wtrans_kernel(const float* __restrict__ wts,
                              float* __restrict__ wtsT) {
    int co = blockIdx.x;
    const float* wrow = wts + (size_t)co * (CI * TAPS);
    for (int k = threadIdx.x; k < CI * TAPS; k += 256) {
        int ci = k / 9, tap = k - ci * 9;
        wtsT[((size_t)tap * CI + ci) * CO + co] = wrow[k];
    }
}

// ---------------------------------------------------------------- sumsq ----
// partial sum over ci for one tap; atomicAdd into sumsq[b][co]
__global__ void sumsq_kernel(const float* __restrict__ wtsT,
                             const float* __restrict__ style,
                             float* __restrict__ sumsq) {
    int tap = blockIdx.x, b = blockIdx.y;
    int co = threadIdx.x;
    const float* st = style + b * CI;
    const float* wp = wtsT + (size_t)tap * CI * CO + co;
    float acc = 0.f;
    for (int ci = 0; ci < CI; ++ci) {
        float v = wp[(size_t)ci * CO] * st[ci];
        acc += v * v;
    }
    atomicAdd(&sumsq[b * CO + co], acc);
}

// ----------------------------------------------------------------- wmod ----
// write demodulated bf16 weights in chunked layout, fully coalesced over co
__global__ void wmod_kernel(const float* __restrict__ wtsT,
                            const float* __restrict__ style,
                            const float* __restrict__ sumsq,
                            bf16x8* __restrict__ wd) {
    int tc = blockIdx.x;            // tap*32 + ci8
    int b = blockIdx.y;
    int tap = tc >> 5, ci8 = tc & 31;
    int co = threadIdx.x;
    float inv = rsqrtf(sumsq[b * CO + co] + EPS);
    const float* st = style + b * CI + ci8 * 8;
    const float* wp = wtsT + ((size_t)tap * CI + ci8 * 8) * CO + co;
    bf16x8 v;
#pragma unroll
    for (int j = 0; j < 8; ++j) v[j] = (bf16)(wp[(size_t)j * CO] * st[j] * inv);
    wd[(((size_t)b * TAPS + tap) * 32 + ci8) * CO + co] = v;
}

// ----------------------------------------------------------------- xpad ----
// x [B][CI][H][W] f32 -> xpad chunks [b][row][ci8][col] (interior rows/cols)
__global__ void xpad_kernel(const float* __restrict__ x, bf16x8* __restrict__ xp) {
    int cc = blockIdx.x;           // ci chunk of 32
    int h = blockIdx.y, b = blockIdx.z;
    __shared__ float t[32][W + 1];
    const float* src = x + ((size_t)b * CI + cc * 32) * (H * W) + (size_t)h * W;
    for (int e = threadIdx.x; e < 32 * W; e += 256) {
        int ci = e >> 6, w = e & 63;
        t[ci][w] = src[(size_t)ci * (H * W) + w];
    }
    __syncthreads();
    int w = threadIdx.x >> 2, sub = threadIdx.x & 3;
    bf16x8 v;
#pragma unroll
    for (int j = 0; j < 8; ++j) v[j] = (bf16)t[sub * 8 + j][w];
    xp[(((size_t)b * PH + h + 1) * 32 + cc * 4 + sub) * PH + (w + 1)] = v;
}

// --------------------------------------------------------------- border ----
__global__ void border_kernel(bf16x8* __restrict__ xp) {
    int row = blockIdx.x, b = blockIdx.y;
    bf16x8* base = xp + ((size_t)b * PH + row) * 32 * PH;
    bf16x8 z;
#pragma unroll
    for (int j = 0; j < 8; ++j) z[j] = (bf16)0.f;
    if (row == 0 || row == PH - 1) {
        for (int c = threadIdx.x; c < 32 * PH; c += 256) base[c] = z;
    } else {
        int tid = threadIdx.x;
        if (tid < 64) {
            int ci8 = tid >> 1, col = (tid & 1) * (PH - 1);
            base[ci8 * PH + col] = z;
        }
    }
}

// ----------------------------------------------------------------- conv ----
// Implicit GEMM, direct-from-global fragments in fragment-native layouts.
// Block 256 thr = 4 waves; block tile 128co x (2 rows x 64 cols);
// wave tile 64co x 64sp = 4x4 mfma_f32_16x16x32_bf16.
// Grid 1D 1024, XCD-pinned: each XCD streams one sample's 3.4MB via its L2.
__global__ void conv_kernel(const bf16x8* __restrict__ wd,
                            const bf16x8* __restrict__ xp,
                            const float* __restrict__ bias,
                            float* __restrict__ out) {
    int i = blockIdx.x;
    int xcd = i & 7, t = i >> 3;               // t: 0..127
    int b = xcd * 2 + (t >> 6);                // one sample at a time per XCD
    int rest = t & 63;
    int cotile = rest & 1, rowpair = rest >> 1;
    int tid = threadIdx.x;
    int wave = tid >> 6, lane = tid & 63;
    int co_half = wave & 1, sp_half = wave >> 1;
    int r = rowpair * 2 + sp_half;             // output row
    int co_base = cotile * 128 + co_half * 64; // + i*16
    int lm = lane & 15, lk = lane >> 4;

    f32x4 acc[4][4] = {};

    const bf16x8* wdb = wd + (size_t)b * TAPS * 32 * CO;
    const bf16x8* xpb = xp + (size_t)b * PH * 32 * PH;

#pragma unroll 1
    for (int c8 = 0; c8 < 32; c8 += 4) {       // ci = (c8+lk)*8 + j
        const bf16x8* wq = wdb + (size_t)(c8 + lk) * CO + co_base + lm;
        const bf16x8* xq = xpb + ((size_t)r * 32 + c8 + lk) * PH + lm;
#pragma unroll
        for (int kh = 0; kh < 3; ++kh) {
#pragma unroll
            for (int kw = 0; kw < 3; ++kw) {
                const int tap = kh * 3 + kw;
                bf16x8 av[4], bv[4];
#pragma unroll
                for (int a = 0; a < 4; ++a)
                    av[a] = wq[(size_t)tap * 32 * CO + a * 16];
#pragma unroll
                for (int j = 0; j < 4; ++j)
                    bv[j] = xq[(size_t)kh * 32 * PH + kw + j * 16];
#pragma unroll
                for (int a = 0; a < 4; ++a)
#pragma unroll
                    for (int j = 0; j < 4; ++j)
                        acc[a][j] = __builtin_amdgcn_mfma_f32_16x16x32_bf16(av[a], bv[j], acc[a][j], 0, 0, 0);
            }
        }
    }

    // epilogue: D col = lm (spatial, + j*16), row = lk*4 + g (co, + a*16)
#pragma unroll
    for (int a = 0; a < 4; ++a) {
#pragma unroll
        for (int g = 0; g < 4; ++g) {
            int co = co_base + a * 16 + lk * 4 + g;
            float bvl = bias[co];
            size_t o = (((size_t)b * CO + co) * H + r) * W;
#pragma unroll
            for (int j = 0; j < 4; ++j)
                out[o + j * 16 + lm] = acc[a][j][g] + bvl;
        }
    }
}

// --------------------------------------------------------------- launch ----
extern "C" void kernel_launch(void* const* d_in, const int* in_sizes, int n_in,
                              void* d_out, int out_size, void* d_ws, size_t ws_size,
                              hipStream_t stream) {
    const float* x    = (const float*)d_in[0];
    const float* y    = (const float*)d_in[1];
    const float* wts  = (const float*)d_in[2];
    const float* bias = (const float*)d_in[3];
    const float* sw   = (const float*)d_in[4];
    const float* sb   = (const float*)d_in[5];
    float* out = (float*)d_out;

    char* ws = (char*)d_ws;
    bf16x8* wd   = (bf16x8*)(ws + WS_WD);
    bf16x8* xpad = (bf16x8*)(ws + WS_XPAD);
    float* style = (float*)(ws + WS_STYLE);
    float* sumsq = (float*)(ws + WS_SUMSQ);
    float* wtsT  = (float*)(ws + WS_WTST);

    style_kernel<<<dim3(B), dim3(CI), 0, stream>>>(y, sw, sb, style);
    wtrans_kernel<<<dim3(CO), dim3(256), 0, stream>>>(wts, wtsT);
    hipMemsetAsync(sumsq, 0, B * CO * sizeof(float), stream);
    sumsq_kernel<<<dim3(TAPS, B), dim3(CO), 0, stream>>>(wtsT, style, sumsq);
    wmod_kernel<<<dim3(TAPS * 32, B), dim3(CO), 0, stream>>>(wtsT, style, sumsq, wd);
    xpad_kernel<<<dim3(CI / 32, H, B), dim3(256), 0, stream>>>(x, xpad);
    border_kernel<<<dim3(PH, B), dim3(256), 0, stream>>>(xpad);
    conv_kernel<<<dim3(1024), dim3(256), 0, stream>>>(wd, xpad, bias, out);
}

// Round 3
// 221.480 us; speedup vs baseline: 1.8681x; 1.1457x over previous
//
#include <hip/hip_runtime.h>

typedef __bf16 bf16;
typedef __bf16 bf16x8 __attribute__((ext_vector_type(8)));
typedef float f32x4 __attribute__((ext_vector_type(4)));

#define EPS 1e-8f

constexpr int B = 16, CI = 256, CO = 256, S = 512, H = 64, W = 64;
constexpr int PH = 66;                    // padded spatial dim
constexpr int TAPS = 9;                   // 3x3

// 16-byte "chunks" (8 bf16):
//   wd   chunks: [tap][ci8=32][co=256]    -> UNMODULATED shared weights, 1.18 MB
//   xpad chunks: [b][row=66][ci8=32][col=66] -> style-scaled input, 35.7 MB
constexpr size_t WS_WD    = 0;                            // 1,179,648 B
constexpr size_t WS_XPAD  = 1179648;
constexpr size_t WS_STYLE = WS_XPAD + (size_t)B*PH*32*PH*16;  // [B][CI] f32
constexpr size_t WS_WSQT  = WS_STYLE + 16384;             // [ci][co] f32 = 256 KB
constexpr size_t WS_INV   = WS_WSQT + 262144;             // [B][CO] f32

// ---------------------------------------------------------------- style ----
// style[b][c] = y[b]·sw[c] + sb[c].  One wave per (b,c): coalesced loads.
__global__ void style_kernel(const float* __restrict__ y,
                             const float* __restrict__ sw,
                             const float* __restrict__ sb,
                             float* __restrict__ style) {
    int b = blockIdx.y;
    int c = blockIdx.x * 4 + (threadIdx.x >> 6);
    int lane = threadIdx.x & 63;
    const float* yr = y + (size_t)b * S;
    const float* wr = sw + (size_t)c * S;
    float acc = 0.f;
#pragma unroll
    for (int k = 0; k < 8; ++k) acc += yr[lane + k * 64] * wr[lane + k * 64];
    for (int off = 32; off; off >>= 1) acc += __shfl_down(acc, off, 64);
    if (lane == 0) style[b * CI + c] = acc + sb[c];
}

// ---------------------------------------------------------------- wprep ----
// wts [CO][CI][3][3] f32 -> wd chunks [tap][ci8][co] bf16 (transpose+cast)
//                        -> wsqT [ci][co] f32 (sum of w^2 over taps)
// Block = 32co x 32ci tile staged in LDS (padded stride 289 vs 288: breaks
// the 32-way bank conflict on the co-major gather).
__global__ void wprep_kernel(const float* __restrict__ wts,
                             bf16x8* __restrict__ wd,
                             float* __restrict__ wsqT) {
    int cb = blockIdx.x;           // co block 0..7
    int ib = blockIdx.y;           // ci block 0..7
    __shared__ float t[32 * 289];
    const float* src = wts + ((size_t)cb * 32) * (CI * TAPS) + ib * 32 * TAPS;
    for (int e = threadIdx.x; e < 32 * 288; e += 256) {
        int col = e / 288, idx = e - col * 288;        // col = co_l
        t[col * 289 + idx] = src[(size_t)col * (CI * TAPS) + idx];
    }
    __syncthreads();
    // wd chunks: tap(9) x ci8_l(4) x co_l(32) = 1152
    for (int c = threadIdx.x; c < 1152; c += 256) {
        int co_l = c & 31, ci8_l = (c >> 5) & 3, tap = c >> 7;
        bf16x8 v;
#pragma unroll
        for (int j = 0; j < 8; ++j) v[j] = (bf16)t[co_l * 289 + (ci8_l * 8 + j) * 9 + tap];
        wd[((size_t)tap * 32 + ib * 4 + ci8_l) * CO + cb * 32 + co_l] = v;
    }
    // wsqT: ci_l(32) x co_l(32)
    for (int c = threadIdx.x; c < 1024; c += 256) {
        int co_l = c & 31, ci_l = c >> 5;
        float s = 0.f;
#pragma unroll
        for (int tap = 0; tap < 9; ++tap) {
            float w = t[co_l * 289 + ci_l * 9 + tap];
            s += w * w;
        }
        wsqT[((size_t)(ib * 32 + ci_l)) * CO + cb * 32 + co_l] = s;
    }
}

// --------------------------------------------------------------- invstd ----
// invstd[b][co] = rsqrt( sum_ci wsqT[ci][co]*st[b][ci]^2 + EPS )
__global__ void invstd_kernel(const float* __restrict__ wsqT,
                              const float* __restrict__ style,
                              float* __restrict__ invstd) {
    int b = blockIdx.x, co = threadIdx.x;
    const float* st = style + b * CI;
    float acc = 0.f;
    for (int ci = 0; ci < CI; ++ci) {
        float s = st[ci];
        acc += wsqT[(size_t)ci * CO + co] * s * s;
    }
    invstd[b * CO + co] = rsqrtf(acc + EPS);
}

// ----------------------------------------------------------------- xpad ----
// x [B][CI][H][W] f32 * style[b][ci] -> xpad chunks [b][row][ci8][col] bf16,
// with zero border rows/cols fused (grid.y covers padded rows 0..65).
__global__ void xpad_kernel(const float* __restrict__ x,
                            const float* __restrict__ style,
                            bf16x8* __restrict__ xp) {
    int cc = blockIdx.x;           // ci chunk of 32
    int hp = blockIdx.y, b = blockIdx.z;
    bf16x8* row = xp + (((size_t)b * PH + hp) * 32) * PH;
    bf16x8 z;
#pragma unroll
    for (int j = 0; j < 8; ++j) z[j] = (bf16)0.f;
    if (hp == 0 || hp == PH - 1) {
        for (int c = threadIdx.x; c < 4 * PH; c += 256) {
            int sub = c / PH, col = c - sub * PH;
            row[(cc * 4 + sub) * PH + col] = z;
        }
        return;
    }
    __shared__ float t[32][W + 1];
    int h = hp - 1;
    const float* src = x + ((size_t)b * CI + cc * 32) * (H * W) + (size_t)h * W;
    const float* st = style + b * CI + cc * 32;
    for (int e = threadIdx.x; e < 32 * W; e += 256) {
        int ci = e >> 6, w = e & 63;
        t[ci][w] = src[(size_t)ci * (H * W) + w] * st[ci];
    }
    __syncthreads();
    int w = threadIdx.x >> 2, sub = threadIdx.x & 3;
    bf16x8 v;
#pragma unroll
    for (int j = 0; j < 8; ++j) v[j] = (bf16)t[sub * 8 + j][w];
    row[(cc * 4 + sub) * PH + (w + 1)] = v;
    if (threadIdx.x < 8) {
        int s2 = threadIdx.x >> 1, col = (threadIdx.x & 1) ? (PH - 1) : 0;
        row[(cc * 4 + s2) * PH + col] = z;
    }
}

// ----------------------------------------------------------------- conv ----
// Implicit GEMM with SHARED unmodulated weights; demod in epilogue.
// Block 256 thr = 4 waves; block tile 128co x (2 rows x 64 cols);
// wave tile 64co x 64sp = 4x4 mfma_f32_16x16x32_bf16.
// Grid 1D 1024, XCD-pinned: wd (1.18 MB) + one sample slice live per-XCD L2.
__global__ void conv_kernel(const bf16x8* __restrict__ wd,
                            const bf16x8* __restrict__ xp,
                            const float* __restrict__ bias,
                            const float* __restrict__ invstd,
                            float* __restrict__ out) {
    int i = blockIdx.x;
    int xcd = i & 7, t = i >> 3;               // t: 0..127
    int b = xcd * 2 + (t >> 6);                // one sample at a time per XCD
    int rest = t & 63;
    int cotile = rest & 1, rowpair = rest >> 1;
    int tid = threadIdx.x;
    int wave = tid >> 6, lane = tid & 63;
    int co_half = wave & 1, sp_half = wave >> 1;
    int r = rowpair * 2 + sp_half;             // output row
    int co_base = cotile * 128 + co_half * 64;
    int lm = lane & 15, lk = lane >> 4;

    f32x4 acc[4][4] = {};

    const bf16x8* xpb = xp + (size_t)b * PH * 32 * PH;

#pragma unroll 1
    for (int c8 = 0; c8 < 32; c8 += 4) {       // ci = (c8+lk)*8 + j
        const bf16x8* wq = wd + (size_t)(c8 + lk) * CO + co_base + lm;
        const bf16x8* xq = xpb + ((size_t)r * 32 + c8 + lk) * PH + lm;
#pragma unroll
        for (int kh = 0; kh < 3; ++kh) {
#pragma unroll
            for (int kw = 0; kw < 3; ++kw) {
                const int tap = kh * 3 + kw;
                bf16x8 av[4], bv[4];
#pragma unroll
                for (int a = 0; a < 4; ++a)
                    av[a] = wq[(size_t)tap * 32 * CO + a * 16];
#pragma unroll
                for (int j = 0; j < 4; ++j)
                    bv[j] = xq[(size_t)kh * 32 * PH + kw + j * 16];
#pragma unroll
                for (int a = 0; a < 4; ++a)
#pragma unroll
                    for (int j = 0; j < 4; ++j)
                        acc[a][j] = __builtin_amdgcn_mfma_f32_16x16x32_bf16(av[a], bv[j], acc[a][j], 0, 0, 0);
            }
        }
    }

    // epilogue: D col = lm (spatial, + j*16), row = lk*4 + g (co, + a*16)
#pragma unroll
    for (int a = 0; a < 4; ++a) {
#pragma unroll
        for (int g = 0; g < 4; ++g) {
            int co = co_base + a * 16 + lk * 4 + g;
            float sc = invstd[b * CO + co];
            float bvl = bias[co];
            size_t o = (((size_t)b * CO + co) * H + r) * W;
#pragma unroll
            for (int j = 0; j < 4; ++j)
                out[o + j * 16 + lm] = acc[a][j][g] * sc + bvl;
        }
    }
}

// --------------------------------------------------------------- launch ----
extern "C" void kernel_launch(void* const* d_in, const int* in_sizes, int n_in,
                              void* d_out, int out_size, void* d_ws, size_t ws_size,
                              hipStream_t stream) {
    const float* x    = (const float*)d_in[0];
    const float* y    = (const float*)d_in[1];
    const float* wts  = (const float*)d_in[2];
    const float* bias = (const float*)d_in[3];
    const float* sw   = (const float*)d_in[4];
    const float* sb   = (const float*)d_in[5];
    float* out = (float*)d_out;

    char* ws = (char*)d_ws;
    bf16x8* wd    = (bf16x8*)(ws + WS_WD);
    bf16x8* xpad  = (bf16x8*)(ws + WS_XPAD);
    float* style  = (float*)(ws + WS_STYLE);
    float* wsqT   = (float*)(ws + WS_WSQT);
    float* invstd = (float*)(ws + WS_INV);

    style_kernel<<<dim3(CI / 4, B), dim3(256), 0, stream>>>(y, sw, sb, style);
    wprep_kernel<<<dim3(CO / 32, CI / 32), dim3(256), 0, stream>>>(wts, wd, wsqT);
    invstd_kernel<<<dim3(B), dim3(CO), 0, stream>>>(wsqT, style, invstd);
    xpad_kernel<<<dim3(CI / 32, PH, B), dim3(256), 0, stream>>>(x, style, xpad);
    conv_kernel<<<dim3(1024), dim3(256), 0, stream>>>(wd, xpad, bias, invstd, out);
}

// Round 5
// 215.994 us; speedup vs baseline: 1.9155x; 1.0254x over previous
//
#include <hip/hip_runtime.h>

typedef __bf16 bf16;
typedef __bf16 bf16x8 __attribute__((ext_vector_type(8)));
typedef float f32x4 __attribute__((ext_vector_type(4)));

#define EPS 1e-8f

constexpr int B = 16, CI = 256, CO = 256, S = 512, H = 64, W = 64;
constexpr int PH = 66;                    // padded spatial dim
constexpr int TAPS = 9;                   // 3x3

// 16-byte "chunks" (8 bf16):
//   wd   chunks: [tap][ci8=32][co=256]    -> UNMODULATED shared weights, 1.18 MB
//   xpad chunks: [b][row=66][ci8=32][col=66] -> style-scaled input, 35.7 MB
constexpr size_t WS_WD    = 0;                            // 1,179,648 B
constexpr size_t WS_XPAD  = 1179648;
constexpr size_t WS_STYLE = WS_XPAD + (size_t)B*PH*32*PH*16;  // [B][CI] f32
constexpr size_t WS_WSQT  = WS_STYLE + 16384;             // [ci][co] f32 = 256 KB
constexpr size_t WS_INV   = WS_WSQT + 262144;             // [B][CO] f32

// ---------------------------------------------------------------- style ----
// style[b][c] = y[b]·sw[c] + sb[c].  One wave per (b,c): coalesced loads.
__global__ void style_kernel(const float* __restrict__ y,
                             const float* __restrict__ sw,
                             const float* __restrict__ sb,
                             float* __restrict__ style) {
    int b = blockIdx.y;
    int c = blockIdx.x * 4 + (threadIdx.x >> 6);
    int lane = threadIdx.x & 63;
    const float* yr = y + (size_t)b * S;
    const float* wr = sw + (size_t)c * S;
    float acc = 0.f;
#pragma unroll
    for (int k = 0; k < 8; ++k) acc += yr[lane + k * 64] * wr[lane + k * 64];
    for (int off = 32; off; off >>= 1) acc += __shfl_down(acc, off, 64);
    if (lane == 0) style[b * CI + c] = acc + sb[c];
}

// ---------------------------------------------------------------- wprep ----
// wts [CO][CI][3][3] f32 -> wd chunks [tap][ci8][co] bf16 (transpose+cast)
//                        -> wsqT [ci][co] f32 (sum of w^2 over taps)
// 8co x 32ci tile per block; grid 32x8 = 256 blocks (full CU coverage).
__global__ void wprep_kernel(const float* __restrict__ wts,
                             bf16x8* __restrict__ wd,
                             float* __restrict__ wsqT) {
    int cb = blockIdx.x;           // co block 0..31 (8 co each)
    int ib = blockIdx.y;           // ci block 0..7  (32 ci each)
    __shared__ float t[8 * 289];   // stride 289: bank-conflict-free gathers
    const float* src = wts + ((size_t)cb * 8) * (CI * TAPS) + ib * 32 * TAPS;
    for (int e = threadIdx.x; e < 8 * 288; e += 256) {
        int col = e / 288, idx = e - col * 288;        // col = co_l
        t[col * 289 + idx] = src[(size_t)col * (CI * TAPS) + idx];
    }
    __syncthreads();
    // wd chunks: tap(9) x ci8_l(4) x co_l(8) = 288  (strided loop: 288 > 256!)
    for (int c = threadIdx.x; c < 288; c += 256) {
        int co_l = c & 7, ci8_l = (c >> 3) & 3, tap = c >> 5;
        bf16x8 v;
#pragma unroll
        for (int j = 0; j < 8; ++j) v[j] = (bf16)t[co_l * 289 + (ci8_l * 8 + j) * 9 + tap];
        wd[((size_t)tap * 32 + ib * 4 + ci8_l) * CO + cb * 8 + co_l] = v;
    }
    // wsqT: ci_l(32) x co_l(8) = 256
    {
        int c = threadIdx.x;
        int co_l = c & 7, ci_l = c >> 3;
        float s = 0.f;
#pragma unroll
        for (int tap = 0; tap < 9; ++tap) {
            float w = t[co_l * 289 + ci_l * 9 + tap];
            s += w * w;
        }
        wsqT[((size_t)(ib * 32 + ci_l)) * CO + cb * 8 + co_l] = s;
    }
}

// --------------------------------------------------------------- invstd ----
// invstd[b][co] = rsqrt( sum_ci wsqT[ci][co]*st[b][ci]^2 + EPS )
__global__ void invstd_kernel(const float* __restrict__ wsqT,
                              const float* __restrict__ style,
                              float* __restrict__ invstd) {
    int b = blockIdx.x, co = threadIdx.x;
    const float* st = style + b * CI;
    float acc = 0.f;
    for (int ci = 0; ci < CI; ++ci) {
        float s = st[ci];
        acc += wsqT[(size_t)ci * CO + co] * s * s;
    }
    invstd[b * CO + co] = rsqrtf(acc + EPS);
}

// ----------------------------------------------------------------- xpad ----
// x [B][CI][H][W] f32 * style[b][ci] -> xpad chunks [b][row][ci8][col] bf16.
// Block: 32 ci x 4 rows (32 KB float4 reads, coalesced 1KB chunk stores).
// grid (8, 17, 16): yb<16 = 4 data rows; yb==16 = zero border rows 0 & 65.
__global__ void xpad_kernel(const float* __restrict__ x,
                            const float* __restrict__ style,
                            bf16x8* __restrict__ xp) {
    int cc = blockIdx.x;           // ci chunk of 32
    int yb = blockIdx.y, b = blockIdx.z;
    bf16x8 z;
#pragma unroll
    for (int j = 0; j < 8; ++j) z[j] = (bf16)0.f;

    if (yb == 16) {                // padded rows 0 and 65: 2 x 4 x 66 chunks
        for (int q = threadIdx.x; q < 2 * 4 * PH; q += 256) {
            int row = (q >= 4 * PH) ? (PH - 1) : 0;
            int rest = (q >= 4 * PH) ? q - 4 * PH : q;
            int sub = rest / PH, col = rest - sub * PH;
            xp[(((size_t)b * PH + row) * 32 + cc * 4 + sub) * PH + col] = z;
        }
        return;
    }

    int h0 = yb * 4;
    __shared__ float t[4][32][W + 1];   // stride 65 words: 2-way (free) access
    const float* xb = x + ((size_t)b * CI + cc * 32) * (H * W);
    const float* st = style + b * CI + cc * 32;
#pragma unroll
    for (int k = 0; k < 8; ++k) {
        int idx = threadIdx.x + k * 256;          // < 2048 float4s
        int w4 = idx & 15, ci = (idx >> 4) & 31, r = idx >> 9;
        f32x4 v = *(const f32x4*)(xb + ((size_t)ci * H + h0 + r) * W + w4 * 4);
        float s = st[ci];
        t[r][ci][w4 * 4 + 0] = v.x * s;
        t[r][ci][w4 * 4 + 1] = v.y * s;
        t[r][ci][w4 * 4 + 2] = v.z * s;
        t[r][ci][w4 * 4 + 3] = v.w * s;
    }
    __syncthreads();
#pragma unroll
    for (int k = 0; k < 4; ++k) {
        int q = threadIdx.x + k * 256;            // < 1024 chunks
        int w = q & 63, sub = (q >> 6) & 3, r = q >> 8;
        bf16x8 v;
#pragma unroll
        for (int j = 0; j < 8; ++j) v[j] = (bf16)t[r][sub * 8 + j][w];
        xp[(((size_t)b * PH + h0 + r + 1) * 32 + cc * 4 + sub) * PH + (w + 1)] = v;
    }
    if (threadIdx.x < 32) {                       // border cols for these rows
        int r = threadIdx.x >> 3, sub = (threadIdx.x >> 1) & 3;
        int col = (threadIdx.x & 1) ? (PH - 1) : 0;
        xp[(((size_t)b * PH + h0 + r + 1) * 32 + cc * 4 + sub) * PH + col] = z;
    }
}

// ----------------------------------------------------------------- conv ----
// Implicit GEMM with SHARED unmodulated weights; demod in epilogue.
// Block 256 thr = 4 waves; block tile 128co x (2 rows x 64 cols);
// wave tile 64co x 64sp = 4x4 mfma_f32_16x16x32_bf16.
// Grid 1D 1024, XCD-pinned: wd (1.18 MB) + one sample slice live per-XCD L2.
__global__ void conv_kernel(const bf16x8* __restrict__ wd,
                            const bf16x8* __restrict__ xp,
                            const float* __restrict__ bias,
                            const float* __restrict__ invstd,
                            float* __restrict__ out) {
    int i = blockIdx.x;
    int xcd = i & 7, t = i >> 3;               // t: 0..127
    int b = xcd * 2 + (t >> 6);                // one sample at a time per XCD
    int rest = t & 63;
    int cotile = rest & 1, rowpair = rest >> 1;
    int tid = threadIdx.x;
    int wave = tid >> 6, lane = tid & 63;
    int co_half = wave & 1, sp_half = wave >> 1;
    int r = rowpair * 2 + sp_half;             // output row
    int co_base = cotile * 128 + co_half * 64;
    int lm = lane & 15, lk = lane >> 4;

    f32x4 acc[4][4] = {};

    const bf16x8* xpb = xp + (size_t)b * PH * 32 * PH;

#pragma unroll 1
    for (int c8 = 0; c8 < 32; c8 += 4) {       // ci = (c8+lk)*8 + j
        const bf16x8* wq = wd + (size_t)(c8 + lk) * CO + co_base + lm;
        const bf16x8* xq = xpb + ((size_t)r * 32 + c8 + lk) * PH + lm;
#pragma unroll
        for (int kh = 0; kh < 3; ++kh) {
#pragma unroll
            for (int kw = 0; kw < 3; ++kw) {
                const int tap = kh * 3 + kw;
                bf16x8 av[4], bv[4];
#pragma unroll
                for (int a = 0; a < 4; ++a)
                    av[a] = wq[(size_t)tap * 32 * CO + a * 16];
#pragma unroll
                for (int j = 0; j < 4; ++j)
                    bv[j] = xq[(size_t)kh * 32 * PH + kw + j * 16];
#pragma unroll
                for (int a = 0; a < 4; ++a)
#pragma unroll
                    for (int j = 0; j < 4; ++j)
                        acc[a][j] = __builtin_amdgcn_mfma_f32_16x16x32_bf16(av[a], bv[j], acc[a][j], 0, 0, 0);
            }
        }
    }

    // epilogue: D col = lm (spatial, + j*16), row = lk*4 + g (co, + a*16)
#pragma unroll
    for (int a = 0; a < 4; ++a) {
#pragma unroll
        for (int g = 0; g < 4; ++g) {
            int co = co_base + a * 16 + lk * 4 + g;
            float sc = invstd[b * CO + co];
            float bvl = bias[co];
            size_t o = (((size_t)b * CO + co) * H + r) * W;
#pragma unroll
            for (int j = 0; j < 4; ++j)
                out[o + j * 16 + lm] = acc[a][j][g] * sc + bvl;
        }
    }
}

// --------------------------------------------------------------- launch ----
extern "C" void kernel_launch(void* const* d_in, const int* in_sizes, int n_in,
                              void* d_out, int out_size, void* d_ws, size_t ws_size,
                              hipStream_t stream) {
    const float* x    = (const float*)d_in[0];
    const float* y    = (const float*)d_in[1];
    const float* wts  = (const float*)d_in[2];
    const float* bias = (const float*)d_in[3];
    const float* sw   = (const float*)d_in[4];
    const float* sb   = (const float*)d_in[5];
    float* out = (float*)d_out;

    char* ws = (char*)d_ws;
    bf16x8* wd    = (bf16x8*)(ws + WS_WD);
    bf16x8* xpad  = (bf16x8*)(ws + WS_XPAD);
    float* style  = (float*)(ws + WS_STYLE);
    float* wsqT   = (float*)(ws + WS_WSQT);
    float* invstd = (float*)(ws + WS_INV);

    style_kernel<<<dim3(CI / 4, B), dim3(256), 0, stream>>>(y, sw, sb, style);
    wprep_kernel<<<dim3(CO / 8, CI / 32), dim3(256), 0, stream>>>(wts, wd, wsqT);
    xpad_kernel<<<dim3(CI / 32, 17, B), dim3(256), 0, stream>>>(x, style, xpad);
    invstd_kernel<<<dim3(B), dim3(CO), 0, stream>>>(wsqT, style, invstd);
    conv_kernel<<<dim3(1024), dim3(256), 0, stream>>>(wd, xpad, bias, invstd, out);
}

// Round 6
// 207.935 us; speedup vs baseline: 1.9898x; 1.0388x over previous
//
#include <hip/hip_runtime.h>

typedef __bf16 bf16;
typedef __bf16 bf16x8 __attribute__((ext_vector_type(8)));
typedef float f32x4 __attribute__((ext_vector_type(4)));

#define EPS 1e-8f

constexpr int B = 16, CI = 256, CO = 256, S = 512, H = 64, W = 64;
constexpr int PH = 66;                    // padded spatial dim
constexpr int TAPS = 9;                   // 3x3

// 16-byte "chunks" (8 bf16):
//   wd   chunks: [tap][ci8=32][co=256]    -> UNMODULATED shared weights, 1.18 MB
//   xpad chunks: [b][row=66][ci8=32][col=66] -> style-scaled input, 35.7 MB
constexpr size_t WS_WD    = 0;                            // 1,179,648 B
constexpr size_t WS_XPAD  = 1179648;
constexpr size_t WS_STYLE = WS_XPAD + (size_t)B*PH*32*PH*16;  // [B][CI] f32
constexpr size_t WS_WSQT  = WS_STYLE + 16384;             // [ci][co] f32 = 256 KB
constexpr size_t WS_INV   = WS_WSQT + 262144;             // [B][CO] f32

// ---------------------------------------------------------------- prep1 ----
// blocks 0..255:    wprep  — wts [CO][CI][3][3] f32 -> wd chunks + wsqT
// blocks 256..1279: style  — style[b][c] = y[b]·sw[c] + sb[c]
__global__ void prep1_kernel(const float* __restrict__ y,
                             const float* __restrict__ sw,
                             const float* __restrict__ sb,
                             const float* __restrict__ wts,
                             bf16x8* __restrict__ wd,
                             float* __restrict__ wsqT,
                             float* __restrict__ style) {
    __shared__ float t[8 * 289];   // stride 289: bank-conflict-free gathers
    int i = blockIdx.x;
    if (i < 256) {                 // ---- wprep: 8co x 32ci tile ----
        int cb = i & 31;           // co block 0..31 (8 co each)
        int ib = i >> 5;           // ci block 0..7  (32 ci each)
        const float* src = wts + ((size_t)cb * 8) * (CI * TAPS) + ib * 32 * TAPS;
        for (int e = threadIdx.x; e < 8 * 288; e += 256) {
            int col = e / 288, idx = e - col * 288;        // col = co_l
            t[col * 289 + idx] = src[(size_t)col * (CI * TAPS) + idx];
        }
        __syncthreads();
        // wd chunks: tap(9) x ci8_l(4) x co_l(8) = 288 (strided: 288 > 256)
        for (int c = threadIdx.x; c < 288; c += 256) {
            int co_l = c & 7, ci8_l = (c >> 3) & 3, tap = c >> 5;
            bf16x8 v;
#pragma unroll
            for (int j = 0; j < 8; ++j) v[j] = (bf16)t[co_l * 289 + (ci8_l * 8 + j) * 9 + tap];
            wd[((size_t)tap * 32 + ib * 4 + ci8_l) * CO + cb * 8 + co_l] = v;
        }
        // wsqT: ci_l(32) x co_l(8) = 256
        int c = threadIdx.x;
        int co_l = c & 7, ci_l = c >> 3;
        float s = 0.f;
#pragma unroll
        for (int tap = 0; tap < 9; ++tap) {
            float w = t[co_l * 289 + ci_l * 9 + tap];
            s += w * w;
        }
        wsqT[((size_t)(ib * 32 + ci_l)) * CO + cb * 8 + co_l] = s;
    } else {                       // ---- style: one wave per (b,c) ----
        int i2 = i - 256;
        int b = i2 >> 6;
        int c = (i2 & 63) * 4 + (threadIdx.x >> 6);
        int lane = threadIdx.x & 63;
        const float* yr = y + (size_t)b * S;
        const float* wr = sw + (size_t)c * S;
        float acc = 0.f;
#pragma unroll
        for (int k = 0; k < 8; ++k) acc += yr[lane + k * 64] * wr[lane + k * 64];
        for (int off = 32; off; off >>= 1) acc += __shfl_down(acc, off, 64);
        if (lane == 0) style[b * CI + c] = acc + sb[c];
    }
}

// ---------------------------------------------------------------- prep2 ----
// blocks 0..2175:    xpad   — x * style -> xpad chunks (4 rows x 32 ci each;
//                    yb==16 writes the zero border rows 0 & 65)
// blocks 2176..2191: invstd — rsqrt(sum_ci wsqT[ci][co]*st^2 + EPS)
__global__ void prep2_kernel(const float* __restrict__ x,
                             const float* __restrict__ style,
                             const float* __restrict__ wsqT,
                             bf16x8* __restrict__ xp,
                             float* __restrict__ invstd) {
    __shared__ float t[4][32][W + 1];   // stride 65 words: 2-way (free)
    int i = blockIdx.x;
    if (i >= 2176) {               // ---- invstd ----
        int b = i - 2176, co = threadIdx.x;
        const float* st = style + b * CI;
        float acc = 0.f;
        for (int ci = 0; ci < CI; ++ci) {
            float s = st[ci];
            acc += wsqT[(size_t)ci * CO + co] * s * s;
        }
        invstd[b * CO + co] = rsqrtf(acc + EPS);
        return;
    }
    // ---- xpad ----
    int cc = i & 7;                // ci chunk of 32
    int u = i >> 3;
    int yb = u % 17, b = u / 17;
    bf16x8 z;
#pragma unroll
    for (int j = 0; j < 8; ++j) z[j] = (bf16)0.f;

    if (yb == 16) {                // padded rows 0 and 65: 2 x 4 x 66 chunks
        for (int q = threadIdx.x; q < 2 * 4 * PH; q += 256) {
            int row = (q >= 4 * PH) ? (PH - 1) : 0;
            int rest = (q >= 4 * PH) ? q - 4 * PH : q;
            int sub = rest / PH, col = rest - sub * PH;
            xp[(((size_t)b * PH + row) * 32 + cc * 4 + sub) * PH + col] = z;
        }
        return;
    }

    int h0 = yb * 4;
    const float* xb = x + ((size_t)b * CI + cc * 32) * (H * W);
    const float* st = style + b * CI + cc * 32;
#pragma unroll
    for (int k = 0; k < 8; ++k) {
        int idx = threadIdx.x + k * 256;          // < 2048 float4s
        int w4 = idx & 15, ci = (idx >> 4) & 31, r = idx >> 9;
        f32x4 v = *(const f32x4*)(xb + ((size_t)ci * H + h0 + r) * W + w4 * 4);
        float s = st[ci];
        t[r][ci][w4 * 4 + 0] = v.x * s;
        t[r][ci][w4 * 4 + 1] = v.y * s;
        t[r][ci][w4 * 4 + 2] = v.z * s;
        t[r][ci][w4 * 4 + 3] = v.w * s;
    }
    __syncthreads();
#pragma unroll
    for (int k = 0; k < 4; ++k) {
        int q = threadIdx.x + k * 256;            // < 1024 chunks
        int w = q & 63, sub = (q >> 6) & 3, r = q >> 8;
        bf16x8 v;
#pragma unroll
        for (int j = 0; j < 8; ++j) v[j] = (bf16)t[r][sub * 8 + j][w];
        xp[(((size_t)b * PH + h0 + r + 1) * 32 + cc * 4 + sub) * PH + (w + 1)] = v;
    }
    if (threadIdx.x < 32) {                       // border cols for these rows
        int r = threadIdx.x >> 3, sub = (threadIdx.x >> 1) & 3;
        int col = (threadIdx.x & 1) ? (PH - 1) : 0;
        xp[(((size_t)b * PH + h0 + r + 1) * 32 + cc * 4 + sub) * PH + col] = z;
    }
}

// ----------------------------------------------------------------- conv ----
// Implicit GEMM with SHARED unmodulated weights; demod in epilogue.
// Block 256 thr = 4 waves; block tile 128co x (2 rows x 64 cols);
// wave tile 64co x 64sp = 4x4 mfma_f32_16x16x32_bf16.
// Grid 1D 1024, XCD-pinned: wd (1.18 MB) + one sample slice live per-XCD L2.
// (Byte-identical to round 5 for attribution.)
__global__ void conv_kernel(const bf16x8* __restrict__ wd,
                            const bf16x8* __restrict__ xp,
                            const float* __restrict__ bias,
                            const float* __restrict__ invstd,
                            float* __restrict__ out) {
    int i = blockIdx.x;
    int xcd = i & 7, t = i >> 3;               // t: 0..127
    int b = xcd * 2 + (t >> 6);                // one sample at a time per XCD
    int rest = t & 63;
    int cotile = rest & 1, rowpair = rest >> 1;
    int tid = threadIdx.x;
    int wave = tid >> 6, lane = tid & 63;
    int co_half = wave & 1, sp_half = wave >> 1;
    int r = rowpair * 2 + sp_half;             // output row
    int co_base = cotile * 128 + co_half * 64;
    int lm = lane & 15, lk = lane >> 4;

    f32x4 acc[4][4] = {};

    const bf16x8* xpb = xp + (size_t)b * PH * 32 * PH;

#pragma unroll 1
    for (int c8 = 0; c8 < 32; c8 += 4) {       // ci = (c8+lk)*8 + j
        const bf16x8* wq = wd + (size_t)(c8 + lk) * CO + co_base + lm;
        const bf16x8* xq = xpb + ((size_t)r * 32 + c8 + lk) * PH + lm;
#pragma unroll
        for (int kh = 0; kh < 3; ++kh) {
#pragma unroll
            for (int kw = 0; kw < 3; ++kw) {
                const int tap = kh * 3 + kw;
                bf16x8 av[4], bv[4];
#pragma unroll
                for (int a = 0; a < 4; ++a)
                    av[a] = wq[(size_t)tap * 32 * CO + a * 16];
#pragma unroll
                for (int j = 0; j < 4; ++j)
                    bv[j] = xq[(size_t)kh * 32 * PH + kw + j * 16];
#pragma unroll
                for (int a = 0; a < 4; ++a)
#pragma unroll
                    for (int j = 0; j < 4; ++j)
                        acc[a][j] = __builtin_amdgcn_mfma_f32_16x16x32_bf16(av[a], bv[j], acc[a][j], 0, 0, 0);
            }
        }
    }

    // epilogue: D col = lm (spatial, + j*16), row = lk*4 + g (co, + a*16)
#pragma unroll
    for (int a = 0; a < 4; ++a) {
#pragma unroll
        for (int g = 0; g < 4; ++g) {
            int co = co_base + a * 16 + lk * 4 + g;
            float sc = invstd[b * CO + co];
            float bvl = bias[co];
            size_t o = (((size_t)b * CO + co) * H + r) * W;
#pragma unroll
            for (int j = 0; j < 4; ++j)
                out[o + j * 16 + lm] = acc[a][j][g] * sc + bvl;
        }
    }
}

// --------------------------------------------------------------- launch ----
extern "C" void kernel_launch(void* const* d_in, const int* in_sizes, int n_in,
                              void* d_out, int out_size, void* d_ws, size_t ws_size,
                              hipStream_t stream) {
    const float* x    = (const float*)d_in[0];
    const float* y    = (const float*)d_in[1];
    const float* wts  = (const float*)d_in[2];
    const float* bias = (const float*)d_in[3];
    const float* sw   = (const float*)d_in[4];
    const float* sb   = (const float*)d_in[5];
    float* out = (float*)d_out;

    char* ws = (char*)d_ws;
    bf16x8* wd    = (bf16x8*)(ws + WS_WD);
    bf16x8* xpad  = (bf16x8*)(ws + WS_XPAD);
    float* style  = (float*)(ws + WS_STYLE);
    float* wsqT   = (float*)(ws + WS_WSQT);
    float* invstd = (float*)(ws + WS_INV);

    prep1_kernel<<<dim3(1280), dim3(256), 0, stream>>>(y, sw, sb, wts, wd, wsqT, style);
    prep2_kernel<<<dim3(2192), dim3(256), 0, stream>>>(x, style, wsqT, xpad, invstd);
    conv_kernel<<<dim3(1024), dim3(256), 0, stream>>>(wd, xpad, bias, invstd, out);
}